// Round 11
// baseline (51.060 us; speedup 1.0000x reference)
//
#include <hip/hip_runtime.h>
#include <hip/hip_bf16.h>

static constexpr int kC = 256;
static constexpr int kN = 1024;   // H*W

using s16x8 = __attribute__((ext_vector_type(8))) short;
using f32x4 = __attribute__((ext_vector_type(4))) float;
using u32x4 = __attribute__((ext_vector_type(4))) unsigned int;

__device__ inline f32x4 mfma16(s16x8 a, s16x8 b, f32x4 c) {
  return __builtin_amdgcn_mfma_f32_16x16x32_bf16(a, b, c, 0, 0, 0);
}

__device__ inline unsigned short f2bf(float f) {   // RNE
  unsigned u = __builtin_bit_cast(unsigned, f);
  u = (u + 0x7fffu + ((u >> 16) & 1u)) >> 16;
  return (unsigned short)u;
}

__device__ inline float exp2_fast(float x) {   // 2^x, single v_exp_f32
  float r;
  asm("v_exp_f32 %0, %1" : "=v"(r) : "v"(x));
  return r;
}

__device__ inline unsigned cvt_pk_bf16(float lo, float hi) {
  unsigned r;
  asm("v_cvt_pk_bf16_f32 %0, %1, %2" : "=v"(r) : "v"(lo), "v"(hi));
  return r;
}

// Async global->LDS, 16B per lane: LDS dest = uniform base + lane*16;
// global source is per-lane (we pass lane-adjusted src).
__device__ inline void gl_lds16(const void* g, void* l) {
  typedef __attribute__((address_space(1))) const unsigned int GU;
  typedef __attribute__((address_space(3))) unsigned int LU;
  __builtin_amdgcn_global_load_lds((GU*)g, (LU*)l, 16, 0, 0);
}

// 1/sqrt(64) * log2(e): folded into Q so QK^T lands in exp2 units.
static constexpr float kQScale = 0.18033688011112042f;

// ---------------------------------------------------------------------------
// prep: blocks 0..127 pack weights into A-frag layout; blocks 128..383 GN.
// ---------------------------------------------------------------------------
__global__ __launch_bounds__(256) void prep_kernel(
    const float* __restrict__ x, const float* __restrict__ gamma,
    const float* __restrict__ beta, unsigned short* __restrict__ hTp,
    const float* __restrict__ wq, const float* __restrict__ wp,
    unsigned short* __restrict__ Wqp, unsigned short* __restrict__ Wpp) {
  if (blockIdx.x < 128) {
    const int tid = blockIdx.x * 256 + threadIdx.x;   // 0..32767
    const float* src;
    unsigned short* dst;
    if (tid < 24576) {
      const int fragid = tid >> 6, lane = tid & 63;
      const int Mt = fragid >> 3, kt = fragid & 7;
      src = wq + (size_t)(Mt * 16 + (lane & 15)) * 256 + kt * 32 + (lane >> 4) * 8;
      dst = Wqp + (size_t)tid * 8;
    } else {
      const int id = tid - 24576;
      const int fragid = id >> 6, lane = id & 63;
      const int Mt = fragid >> 3, kt = fragid & 7;
      src = wp + (size_t)(Mt * 16 + (lane & 15)) * 256 + kt * 32 + (lane >> 4) * 8;
      dst = Wpp + (size_t)id * 8;
    }
    const float4 f0 = *(const float4*)src;
    const float4 f1 = *(const float4*)(src + 4);
    ushort4 o0, o1;
    o0.x = f2bf(f0.x); o0.y = f2bf(f0.y); o0.z = f2bf(f0.z); o0.w = f2bf(f0.w);
    o1.x = f2bf(f1.x); o1.y = f2bf(f1.y); o1.z = f2bf(f1.z); o1.w = f2bf(f1.w);
    *(ushort4*)dst = o0;
    *(ushort4*)(dst + 4) = o1;
    return;
  }

  const int bg = blockIdx.x - 128;
  const int b = bg & 7, g = bg >> 3;   // batch = XCD
  const size_t base = ((size_t)b * kC + (size_t)g * 8) * kN;
  const float4* __restrict__ x4 = (const float4*)(x + base);
  const int t = threadIdx.x;

  float vv[8][4];
  float s = 0.f, ss = 0.f;
#pragma unroll
  for (int i = 0; i < 8; ++i) {
    const float4 v = x4[t + 256 * i];
    vv[i][0] = v.x; vv[i][1] = v.y; vv[i][2] = v.z; vv[i][3] = v.w;
    s += v.x + v.y + v.z + v.w;
    ss += v.x * v.x + v.y * v.y + v.z * v.z + v.w * v.w;
  }
#pragma unroll
  for (int off = 32; off > 0; off >>= 1) {
    s += __shfl_xor(s, off);
    ss += __shfl_xor(ss, off);
  }
  __shared__ float rs[4], rss[4];
  const int wave = t >> 6, lane = t & 63;
  if (lane == 0) { rs[wave] = s; rss[wave] = ss; }
  __syncthreads();
  s = rs[0] + rs[1] + rs[2] + rs[3];
  ss = rss[0] + rss[1] + rss[2] + rss[3];
  const float mean = s * (1.f / 8192.f);
  const float var = ss * (1.f / 8192.f) - mean * mean;
  const float rinv = rsqrtf(var + 1e-5f);
  float ga[8], be[8];
#pragma unroll
  for (int i = 0; i < 8; ++i) {
    ga[i] = gamma[g * 8 + i] * rinv;
    be[i] = beta[g * 8 + i] - mean * ga[i];
  }
  const int kt = g >> 2, gq = g & 3;
#pragma unroll
  for (int r = 0; r < 4; ++r) {
    const int pos = 4 * t + r;
    const int nt = pos >> 4, lp = pos & 15;
    unsigned short* dst =
        hTp + ((size_t)((b * 64 + nt) * 8 + kt) * 64 + (gq * 16 + lp)) * 8;
    ushort4 o0, o1;
    o0.x = f2bf(vv[0][r] * ga[0] + be[0]);
    o0.y = f2bf(vv[1][r] * ga[1] + be[1]);
    o0.z = f2bf(vv[2][r] * ga[2] + be[2]);
    o0.w = f2bf(vv[3][r] * ga[3] + be[3]);
    o1.x = f2bf(vv[4][r] * ga[4] + be[4]);
    o1.y = f2bf(vv[5][r] * ga[5] + be[5]);
    o1.z = f2bf(vv[6][r] * ga[6] + be[6]);
    o1.w = f2bf(vv[7][r] * ga[7] + be[7]);
    *(ushort4*)dst = o0;
    *(ushort4*)(dst + 4) = o1;
  }
}

// ---------------------------------------------------------------------------
// LDS-free bf16 MFMA QKV GEMM, depth-3 register prefetch (4 rotating slots).
// Block: 4 waves (2m x 2n), tile 128m x 64n; wave 64m x 32n; K=256.
// V stored sigma-permuted so attention's P registers are directly the PV
// B-frag (no LDS round trip).
// ---------------------------------------------------------------------------
__device__ inline void gload(const s16x8* __restrict__ Af,
                             const s16x8* __restrict__ Bf,
                             int Mt0, int Nt0, int kt, int lane,
                             s16x8 (&a)[4], s16x8 (&bb)[2]) {
#pragma unroll
  for (int mt = 0; mt < 4; ++mt)
    a[mt] = Af[((size_t)(Mt0 + mt) * 8 + kt) * 64 + lane];
#pragma unroll
  for (int nt = 0; nt < 2; ++nt)
    bb[nt] = Bf[((size_t)(Nt0 + nt) * 8 + kt) * 64 + lane];
}

__device__ inline void gmfma(const s16x8 (&a)[4], const s16x8 (&bb)[2],
                             f32x4 (&acc)[4][2], bool swap) {
  if (swap) {
#pragma unroll
    for (int mt = 0; mt < 4; ++mt)
#pragma unroll
      for (int nt = 0; nt < 2; ++nt)
        acc[mt][nt] = mfma16(bb[nt], a[mt], acc[mt][nt]);
  } else {
#pragma unroll
    for (int mt = 0; mt < 4; ++mt)
#pragma unroll
      for (int nt = 0; nt < 2; ++nt)
        acc[mt][nt] = mfma16(a[mt], bb[nt], acc[mt][nt]);
  }
}

__global__ __launch_bounds__(256) void gemm_qkv_kernel(
    const unsigned short* __restrict__ Wp, const float* __restrict__ bias,
    const unsigned short* __restrict__ Bp,
    unsigned short* __restrict__ Qp, unsigned short* __restrict__ Kp,
    unsigned short* __restrict__ Vp) {
  const int bid = blockIdx.x;
  const int swz = (bid & 7) * 96 + (bid >> 3);
  const int b = swz / 96, rr = swz % 96;
  const int mb = rr >> 4, nb = rr & 15;
  const int t = threadIdx.x;
  const int wave = t >> 6, lane = t & 63;
  const int li = lane & 15, grp = lane >> 4;
  const int m0 = mb * 128 + (wave >> 1) * 64;
  const int n0 = nb * 64 + (wave & 1) * 32;
  const bool swap = mb >= 4;   // V tiles
  const int Mt0 = m0 >> 4;
  const int Nt0 = b * 64 + (n0 >> 4);
  const s16x8* __restrict__ Af = (const s16x8*)Wp;
  const s16x8* __restrict__ Bf = (const s16x8*)Bp;

  f32x4 acc[4][2];
#pragma unroll
  for (int mt = 0; mt < 4; ++mt)
#pragma unroll
    for (int nt = 0; nt < 2; ++nt) acc[mt][nt] = f32x4{0.f, 0.f, 0.f, 0.f};

  s16x8 sa[4][4], sb[4][2];   // 4 rotating slots, depth-3 prefetch
  gload(Af, Bf, Mt0, Nt0, 0, lane, sa[0], sb[0]);
  gload(Af, Bf, Mt0, Nt0, 1, lane, sa[1], sb[1]);
  gload(Af, Bf, Mt0, Nt0, 2, lane, sa[2], sb[2]);
#pragma unroll
  for (int kt = 0; kt < 8; ++kt) {
    if (kt + 3 < 8)
      gload(Af, Bf, Mt0, Nt0, kt + 3, lane, sa[(kt + 3) & 3], sb[(kt + 3) & 3]);
    gmfma(sa[kt & 3], sb[kt & 3], acc, swap);
  }

  if (!swap) {
    // Q/K: D rows = ch (4grp+r), cols = pos (li). Q gets kQScale folded in.
    unsigned short* __restrict__ Tp = (mb < 2) ? Qp : Kp;
    const float qs = (mb < 2) ? kQScale : 1.0f;
#pragma unroll
    for (int mt = 0; mt < 4; ++mt) {
      const int mbase = m0 + mt * 16;
      const int head = (mbase >> 6) & 3;
      const int bh = b * 4 + head;
      const int c16 = mbase & 63;
      const int ks = c16 >> 5;
      const int grpp = ((c16 >> 3) + (grp >> 1)) & 3;
      const float4 bv = *(const float4*)(bias + mbase + 4 * grp);
#pragma unroll
      for (int nt = 0; nt < 2; ++nt) {
        const int pt = (n0 >> 4) + nt;
        ushort4 o;
        o.x = f2bf((acc[mt][nt][0] + bv.x) * qs);
        o.y = f2bf((acc[mt][nt][1] + bv.y) * qs);
        o.z = f2bf((acc[mt][nt][2] + bv.z) * qs);
        o.w = f2bf((acc[mt][nt][3] + bv.w) * qs);
        *(ushort4*)(Tp + (size_t)bh * 65536 +
                    ((size_t)(pt * 2 + ks) * 64 + grpp * 16 + li) * 8 +
                    (grp & 1) * 4) = o;
      }
    }
  } else {
    // V: D rows = pos (4grp+r), cols = ch (li); sigma-permuted column store.
#pragma unroll
    for (int mt = 0; mt < 4; ++mt) {
      const int mbase = m0 + mt * 16;
      const int head = (mbase >> 6) & 3;
      const int bh = b * 4 + head;
      const int ct = (mbase & 63) >> 4;
      const float bvc = bias[mbase + li];
      const int kvt = n0 >> 5;
#pragma unroll
      for (int nt = 0; nt < 2; ++nt) {
        ushort4 o;
        o.x = f2bf(acc[mt][nt][0] + bvc);
        o.y = f2bf(acc[mt][nt][1] + bvc);
        o.z = f2bf(acc[mt][nt][2] + bvc);
        o.w = f2bf(acc[mt][nt][3] + bvc);
        *(ushort4*)(Vp + (size_t)bh * 65536 +
                    ((size_t)(ct * 32 + kvt) * 64 + grp * 16 + li) * 8 +
                    nt * 4) = o;
      }
    }
  }
}

// ---------------------------------------------------------------------------
// Flash attention with LDS-shared K/V. Block = (bh, 64 q), 4 waves x 16 q.
// Per 32-KV tile: each wave issues 2 global_load_lds (K frag w, V frag w)
// into the double buffer; one barrier per tile; all waves read frags from
// LDS (8x less L2 traffic than private streams). P stays in registers
// (sigma-permuted V). Grid 512 = 8 XCD x 4 bh x 16 qb -> 2 blocks/CU.
// ---------------------------------------------------------------------------
__global__ __launch_bounds__(256) void attn_kernel(
    const unsigned short* __restrict__ Qp, const unsigned short* __restrict__ Kp,
    const unsigned short* __restrict__ Vp, unsigned short* __restrict__ aoTp) {
  __shared__ __align__(16) unsigned short Kl[2][2048];   // 4KB tile x2
  __shared__ __align__(16) unsigned short Vl[2][2048];
  const int bid = blockIdx.x;
  const int xcd = bid & 7, idx = bid >> 3;   // idx 0..63
  const int bh = xcd * 4 + (idx & 3);        // batch b = xcd
  const int qb = idx >> 2;                   // 0..15
  const int b = bh >> 2, head = bh & 3;
  const int t = threadIdx.x;
  const int wave = t >> 6, lane = t & 63;
  const int li = lane & 15, grp = lane >> 4;
  const int q0 = qb * 64 + wave * 16;
  const unsigned short* __restrict__ Qb = Qp + (size_t)bh * 65536;
  const unsigned short* __restrict__ Kb = Kp + (size_t)bh * 65536;
  const unsigned short* __restrict__ Vb = Vp + (size_t)bh * 65536;

  s16x8 qf[2];
#pragma unroll
  for (int ks = 0; ks < 2; ++ks)
    qf[ks] = *(const s16x8*)(Qb + (((q0 >> 4) * 2 + ks) * 64 + lane) * 8);

  f32x4 O[4];
#pragma unroll
  for (int ct = 0; ct < 4; ++ct) O[ct] = f32x4{0.f, 0.f, 0.f, 0.f};
  f32x4 lvec = f32x4{0.f, 0.f, 0.f, 0.f};
  float m_run = -1.0e30f;

  // wave w stages K frag w (contiguous 1KB) and V frag ct=w of tile `it`
  auto stage = [&](int it, int nb) {
    const unsigned short* ksrc = Kb + ((size_t)(it * 4 + wave) * 512 + lane * 8);
    gl_lds16(ksrc, &Kl[nb][wave * 512]);
    const unsigned short* vsrc = Vb + ((size_t)(wave * 32 + it) * 512 + lane * 8);
    gl_lds16(vsrc, &Vl[nb][wave * 512]);
  };

  stage(0, 0);
  __syncthreads();   // drains vmcnt before first reads

  int cb = 0;
#pragma unroll 1
  for (int it = 0; it < 32; ++it) {
    if (it < 31) stage(it + 1, cb ^ 1);   // issue early: covered by compute
    // QK^T from LDS frags
    s16x8 kk[2][2];
#pragma unroll
    for (int mt = 0; mt < 2; ++mt)
#pragma unroll
      for (int ks = 0; ks < 2; ++ks)
        kk[mt][ks] = *(const s16x8*)&Kl[cb][(mt * 2 + ks) * 512 + lane * 8];
    f32x4 s[2];
    __builtin_amdgcn_s_setprio(1);
#pragma unroll
    for (int mt = 0; mt < 2; ++mt) {
      s[mt] = mfma16(kk[mt][0], qf[0], f32x4{0.f, 0.f, 0.f, 0.f});
      s[mt] = mfma16(kk[mt][1], qf[1], s[mt]);
    }
    __builtin_amdgcn_s_setprio(0);
    // online softmax (exp2 units, defer-max)
    const float A = fmaxf(fmaxf(s[0][0], s[0][1]), s[0][2]);
    const float B = fmaxf(fmaxf(s[0][3], s[1][0]), s[1][1]);
    const float C = fmaxf(fmaxf(s[1][2], s[1][3]), A);
    float pm = fmaxf(B, C);
    pm = fmaxf(pm, __shfl_xor(pm, 16));
    pm = fmaxf(pm, __shfl_xor(pm, 32));
    if (!__all(pm <= m_run + 8.0f)) {
      const float mnew = fmaxf(m_run, pm);
      const float f = exp2_fast(m_run - mnew);
      m_run = mnew;
      lvec *= f;
#pragma unroll
      for (int ct = 0; ct < 4; ++ct) O[ct] *= f;
    }
    f32x4 p[2];
#pragma unroll
    for (int mt = 0; mt < 2; ++mt) {
#pragma unroll
      for (int r = 0; r < 4; ++r) p[mt][r] = exp2_fast(s[mt][r] - m_run);
      lvec += p[mt];
    }
    u32x4 pk;
    pk[0] = cvt_pk_bf16(p[0][0], p[0][1]);
    pk[1] = cvt_pk_bf16(p[0][2], p[0][3]);
    pk[2] = cvt_pk_bf16(p[1][0], p[1][1]);
    pk[3] = cvt_pk_bf16(p[1][2], p[1][3]);
    const s16x8 pf = __builtin_bit_cast(s16x8, pk);
    // PV from LDS V frags
    s16x8 vv[4];
#pragma unroll
    for (int ct = 0; ct < 4; ++ct)
      vv[ct] = *(const s16x8*)&Vl[cb][ct * 512 + lane * 8];
    __builtin_amdgcn_s_setprio(1);
#pragma unroll
    for (int ct = 0; ct < 4; ++ct) O[ct] = mfma16(vv[ct], pf, O[ct]);
    __builtin_amdgcn_s_setprio(0);
    __syncthreads();   // staging of cb^1 done; everyone done reading cb
    cb ^= 1;
  }

  float lt = lvec[0] + lvec[1] + lvec[2] + lvec[3];
  lt += __shfl_xor(lt, 16);
  lt += __shfl_xor(lt, 32);
  const float rinv = 1.f / lt;
  // write aoTp packed frags: q = q0+li, c = head*64 + ct*16 + 4*grp + r
#pragma unroll
  for (int ct = 0; ct < 4; ++ct) {
    const int ktp = head * 2 + (ct >> 1);
    const int grpp = ((ct & 1) * 2 + (grp >> 1)) & 3;
    ushort4 o;
    o.x = f2bf(O[ct][0] * rinv);
    o.y = f2bf(O[ct][1] * rinv);
    o.z = f2bf(O[ct][2] * rinv);
    o.w = f2bf(O[ct][3] * rinv);
    *(ushort4*)(aoTp +
                ((size_t)((b * 64 + (q0 >> 4)) * 8 + ktp) * 64 + grpp * 16 + li) * 8 +
                (grp & 1) * 4) = o;
  }
}

// ---------------------------------------------------------------------------
// Proj GEMM: 128m x 64n tiles, K=256, fp32 + bias + residual epilogue.
// ---------------------------------------------------------------------------
__global__ __launch_bounds__(256) void gemm_proj_kernel(
    const unsigned short* __restrict__ Wpp, const float* __restrict__ bias,
    const unsigned short* __restrict__ aoTp, const float* __restrict__ res,
    float* __restrict__ outp) {
  const int bid = blockIdx.x;
  const int swz = (bid & 7) * 32 + (bid >> 3);   // 256 blocks, batch = XCD
  const int b = swz >> 5, rr = swz & 31;
  const int mb = rr >> 4, nb = rr & 15;
  const int t = threadIdx.x;
  const int wave = t >> 6, lane = t & 63;
  const int li = lane & 15, grp = lane >> 4;
  const int m0 = mb * 128 + (wave >> 1) * 64;
  const int n0 = nb * 64 + (wave & 1) * 32;
  const int Mt0 = m0 >> 4;
  const int Nt0 = b * 64 + (n0 >> 4);
  const s16x8* __restrict__ Af = (const s16x8*)Wpp;
  const s16x8* __restrict__ Bf = (const s16x8*)aoTp;

  f32x4 acc[4][2];
#pragma unroll
  for (int mt = 0; mt < 4; ++mt)
#pragma unroll
    for (int nt = 0; nt < 2; ++nt) acc[mt][nt] = f32x4{0.f, 0.f, 0.f, 0.f};

  s16x8 sa[4][4], sb[4][2];
  gload(Af, Bf, Mt0, Nt0, 0, lane, sa[0], sb[0]);
  gload(Af, Bf, Mt0, Nt0, 1, lane, sa[1], sb[1]);
  gload(Af, Bf, Mt0, Nt0, 2, lane, sa[2], sb[2]);
#pragma unroll
  for (int kt = 0; kt < 8; ++kt) {
    if (kt + 3 < 8)
      gload(Af, Bf, Mt0, Nt0, kt + 3, lane, sa[(kt + 3) & 3], sb[(kt + 3) & 3]);
    gmfma(sa[kt & 3], sb[kt & 3], acc, false);
  }

#pragma unroll
  for (int mt = 0; mt < 4; ++mt) {
    const int mbase = m0 + mt * 16 + 4 * grp;
    const float4 bv = *(const float4*)(bias + mbase);
    const float bvr[4] = {bv.x, bv.y, bv.z, bv.w};
#pragma unroll
    for (int nt = 0; nt < 2; ++nt) {
      const int pos = n0 + nt * 16 + li;
#pragma unroll
      for (int r = 0; r < 4; ++r) {
        const size_t ob = ((size_t)(b * 256 + mbase + r)) * 1024 + pos;
        outp[ob] = acc[mt][nt][r] + bvr[r] + res[ob];
      }
    }
  }
}

// ---------------------------------------------------------------------------
extern "C" void kernel_launch(void* const* d_in, const int* in_sizes, int n_in,
                              void* d_out, int out_size, void* d_ws, size_t ws_size,
                              hipStream_t stream) {
  const float* x      = (const float*)d_in[0];
  const float* gamma  = (const float*)d_in[1];
  const float* beta   = (const float*)d_in[2];
  const float* w_qkv  = (const float*)d_in[3];
  const float* b_qkv  = (const float*)d_in[4];
  const float* w_proj = (const float*)d_in[5];
  const float* b_proj = (const float*)d_in[6];
  float* out = (float*)d_out;

  unsigned short* ws = (unsigned short*)d_ws;
  unsigned short* Wqp  = ws;                    // 196608
  unsigned short* Wpp  = Wqp + 196608;          // 65536
  unsigned short* hTp  = Wpp + 65536;           // 2097152
  unsigned short* Qp   = hTp + 2097152;         // 2097152
  unsigned short* Kp   = Qp + 2097152;          // 2097152
  unsigned short* Vp   = Kp + 2097152;          // 2097152
  unsigned short* aoTp = Vp + 2097152;          // 2097152

  hipLaunchKernelGGL(prep_kernel, dim3(384), dim3(256), 0, stream,
                     x, gamma, beta, hTp, w_qkv, w_proj, Wqp, Wpp);
  hipLaunchKernelGGL(gemm_qkv_kernel, dim3(768), dim3(256), 0, stream,
                     Wqp, b_qkv, hTp, Qp, Kp, Vp);
  hipLaunchKernelGGL(attn_kernel, dim3(512), dim3(256), 0, stream,
                     Qp, Kp, Vp, aoTp);
  hipLaunchKernelGGL(gemm_proj_kernel, dim3(256), dim3(256), 0, stream,
                     Wpp, b_proj, aoTp, x, out);
}

// Round 12
// 46.565 us; speedup vs baseline: 1.0965x; 1.0965x over previous
//
#include <hip/hip_runtime.h>
#include <hip/hip_bf16.h>

static constexpr int kC = 256;
static constexpr int kN = 1024;   // H*W

using s16x8 = __attribute__((ext_vector_type(8))) short;
using f32x4 = __attribute__((ext_vector_type(4))) float;
using u32x4 = __attribute__((ext_vector_type(4))) unsigned int;

__device__ inline f32x4 mfma16(s16x8 a, s16x8 b, f32x4 c) {
  return __builtin_amdgcn_mfma_f32_16x16x32_bf16(a, b, c, 0, 0, 0);
}

__device__ inline unsigned short f2bf(float f) {   // RNE
  unsigned u = __builtin_bit_cast(unsigned, f);
  u = (u + 0x7fffu + ((u >> 16) & 1u)) >> 16;
  return (unsigned short)u;
}

__device__ inline float exp2_fast(float x) {   // 2^x, single v_exp_f32
  float r;
  asm("v_exp_f32 %0, %1" : "=v"(r) : "v"(x));
  return r;
}

__device__ inline unsigned cvt_pk_bf16(float lo, float hi) {
  unsigned r;
  asm("v_cvt_pk_bf16_f32 %0, %1, %2" : "=v"(r) : "v"(lo), "v"(hi));
  return r;
}

// 1/sqrt(64) * log2(e): folded into Q so QK^T lands in exp2 units.
static constexpr float kQScale = 0.18033688011112042f;

// ---------------------------------------------------------------------------
// prep: blocks 0..127 pack weights into A-frag layout; blocks 128..383 GN.
// ---------------------------------------------------------------------------
__global__ __launch_bounds__(256) void prep_kernel(
    const float* __restrict__ x, const float* __restrict__ gamma,
    const float* __restrict__ beta, unsigned short* __restrict__ hTp,
    const float* __restrict__ wq, const float* __restrict__ wp,
    unsigned short* __restrict__ Wqp, unsigned short* __restrict__ Wpp) {
  if (blockIdx.x < 128) {
    const int tid = blockIdx.x * 256 + threadIdx.x;   // 0..32767
    const float* src;
    unsigned short* dst;
    if (tid < 24576) {
      const int fragid = tid >> 6, lane = tid & 63;
      const int Mt = fragid >> 3, kt = fragid & 7;
      src = wq + (size_t)(Mt * 16 + (lane & 15)) * 256 + kt * 32 + (lane >> 4) * 8;
      dst = Wqp + (size_t)tid * 8;
    } else {
      const int id = tid - 24576;
      const int fragid = id >> 6, lane = id & 63;
      const int Mt = fragid >> 3, kt = fragid & 7;
      src = wp + (size_t)(Mt * 16 + (lane & 15)) * 256 + kt * 32 + (lane >> 4) * 8;
      dst = Wpp + (size_t)id * 8;
    }
    const float4 f0 = *(const float4*)src;
    const float4 f1 = *(const float4*)(src + 4);
    ushort4 o0, o1;
    o0.x = f2bf(f0.x); o0.y = f2bf(f0.y); o0.z = f2bf(f0.z); o0.w = f2bf(f0.w);
    o1.x = f2bf(f1.x); o1.y = f2bf(f1.y); o1.z = f2bf(f1.z); o1.w = f2bf(f1.w);
    *(ushort4*)dst = o0;
    *(ushort4*)(dst + 4) = o1;
    return;
  }

  const int bg = blockIdx.x - 128;
  const int b = bg & 7, g = bg >> 3;   // batch = XCD
  const size_t base = ((size_t)b * kC + (size_t)g * 8) * kN;
  const float4* __restrict__ x4 = (const float4*)(x + base);
  const int t = threadIdx.x;

  float vv[8][4];
  float s = 0.f, ss = 0.f;
#pragma unroll
  for (int i = 0; i < 8; ++i) {
    const float4 v = x4[t + 256 * i];
    vv[i][0] = v.x; vv[i][1] = v.y; vv[i][2] = v.z; vv[i][3] = v.w;
    s += v.x + v.y + v.z + v.w;
    ss += v.x * v.x + v.y * v.y + v.z * v.z + v.w * v.w;
  }
#pragma unroll
  for (int off = 32; off > 0; off >>= 1) {
    s += __shfl_xor(s, off);
    ss += __shfl_xor(ss, off);
  }
  __shared__ float rs[4], rss[4];
  const int wave = t >> 6, lane = t & 63;
  if (lane == 0) { rs[wave] = s; rss[wave] = ss; }
  __syncthreads();
  s = rs[0] + rs[1] + rs[2] + rs[3];
  ss = rss[0] + rss[1] + rss[2] + rss[3];
  const float mean = s * (1.f / 8192.f);
  const float var = ss * (1.f / 8192.f) - mean * mean;
  const float rinv = rsqrtf(var + 1e-5f);
  float ga[8], be[8];
#pragma unroll
  for (int i = 0; i < 8; ++i) {
    ga[i] = gamma[g * 8 + i] * rinv;
    be[i] = beta[g * 8 + i] - mean * ga[i];
  }
  const int kt = g >> 2, gq = g & 3;
#pragma unroll
  for (int r = 0; r < 4; ++r) {
    const int pos = 4 * t + r;
    const int nt = pos >> 4, lp = pos & 15;
    unsigned short* dst =
        hTp + ((size_t)((b * 64 + nt) * 8 + kt) * 64 + (gq * 16 + lp)) * 8;
    ushort4 o0, o1;
    o0.x = f2bf(vv[0][r] * ga[0] + be[0]);
    o0.y = f2bf(vv[1][r] * ga[1] + be[1]);
    o0.z = f2bf(vv[2][r] * ga[2] + be[2]);
    o0.w = f2bf(vv[3][r] * ga[3] + be[3]);
    o1.x = f2bf(vv[4][r] * ga[4] + be[4]);
    o1.y = f2bf(vv[5][r] * ga[5] + be[5]);
    o1.z = f2bf(vv[6][r] * ga[6] + be[6]);
    o1.w = f2bf(vv[7][r] * ga[7] + be[7]);
    *(ushort4*)dst = o0;
    *(ushort4*)(dst + 4) = o1;
  }
}

// ---------------------------------------------------------------------------
// LDS-free bf16 MFMA QKV GEMM, depth-3 register prefetch (4 rotating slots).
// V stored sigma-permuted so attention's P registers are directly the PV
// B-frag (no LDS round trip).
// ---------------------------------------------------------------------------
__device__ inline void gload(const s16x8* __restrict__ Af,
                             const s16x8* __restrict__ Bf,
                             int Mt0, int Nt0, int kt, int lane,
                             s16x8 (&a)[4], s16x8 (&bb)[2]) {
#pragma unroll
  for (int mt = 0; mt < 4; ++mt)
    a[mt] = Af[((size_t)(Mt0 + mt) * 8 + kt) * 64 + lane];
#pragma unroll
  for (int nt = 0; nt < 2; ++nt)
    bb[nt] = Bf[((size_t)(Nt0 + nt) * 8 + kt) * 64 + lane];
}

__device__ inline void gmfma(const s16x8 (&a)[4], const s16x8 (&bb)[2],
                             f32x4 (&acc)[4][2], bool swap) {
  if (swap) {
#pragma unroll
    for (int mt = 0; mt < 4; ++mt)
#pragma unroll
      for (int nt = 0; nt < 2; ++nt)
        acc[mt][nt] = mfma16(bb[nt], a[mt], acc[mt][nt]);
  } else {
#pragma unroll
    for (int mt = 0; mt < 4; ++mt)
#pragma unroll
      for (int nt = 0; nt < 2; ++nt)
        acc[mt][nt] = mfma16(a[mt], bb[nt], acc[mt][nt]);
  }
}

__global__ __launch_bounds__(256) void gemm_qkv_kernel(
    const unsigned short* __restrict__ Wp, const float* __restrict__ bias,
    const unsigned short* __restrict__ Bp,
    unsigned short* __restrict__ Qp, unsigned short* __restrict__ Kp,
    unsigned short* __restrict__ Vp) {
  const int bid = blockIdx.x;
  const int swz = (bid & 7) * 96 + (bid >> 3);
  const int b = swz / 96, rr = swz % 96;
  const int mb = rr >> 4, nb = rr & 15;
  const int t = threadIdx.x;
  const int wave = t >> 6, lane = t & 63;
  const int li = lane & 15, grp = lane >> 4;
  const int m0 = mb * 128 + (wave >> 1) * 64;
  const int n0 = nb * 64 + (wave & 1) * 32;
  const bool swap = mb >= 4;   // V tiles
  const int Mt0 = m0 >> 4;
  const int Nt0 = b * 64 + (n0 >> 4);
  const s16x8* __restrict__ Af = (const s16x8*)Wp;
  const s16x8* __restrict__ Bf = (const s16x8*)Bp;

  f32x4 acc[4][2];
#pragma unroll
  for (int mt = 0; mt < 4; ++mt)
#pragma unroll
    for (int nt = 0; nt < 2; ++nt) acc[mt][nt] = f32x4{0.f, 0.f, 0.f, 0.f};

  s16x8 sa[4][4], sb[4][2];   // 4 rotating slots, depth-3 prefetch
  gload(Af, Bf, Mt0, Nt0, 0, lane, sa[0], sb[0]);
  gload(Af, Bf, Mt0, Nt0, 1, lane, sa[1], sb[1]);
  gload(Af, Bf, Mt0, Nt0, 2, lane, sa[2], sb[2]);
#pragma unroll
  for (int kt = 0; kt < 8; ++kt) {
    if (kt + 3 < 8)
      gload(Af, Bf, Mt0, Nt0, kt + 3, lane, sa[(kt + 3) & 3], sb[(kt + 3) & 3]);
    gmfma(sa[kt & 3], sb[kt & 3], acc, swap);
  }

  if (!swap) {
    // Q/K: D rows = ch (4grp+r), cols = pos (li). Q gets kQScale folded in.
    unsigned short* __restrict__ Tp = (mb < 2) ? Qp : Kp;
    const float qs = (mb < 2) ? kQScale : 1.0f;
#pragma unroll
    for (int mt = 0; mt < 4; ++mt) {
      const int mbase = m0 + mt * 16;
      const int head = (mbase >> 6) & 3;
      const int bh = b * 4 + head;
      const int c16 = mbase & 63;
      const int ks = c16 >> 5;
      const int grpp = ((c16 >> 3) + (grp >> 1)) & 3;
      const float4 bv = *(const float4*)(bias + mbase + 4 * grp);
#pragma unroll
      for (int nt = 0; nt < 2; ++nt) {
        const int pt = (n0 >> 4) + nt;
        ushort4 o;
        o.x = f2bf((acc[mt][nt][0] + bv.x) * qs);
        o.y = f2bf((acc[mt][nt][1] + bv.y) * qs);
        o.z = f2bf((acc[mt][nt][2] + bv.z) * qs);
        o.w = f2bf((acc[mt][nt][3] + bv.w) * qs);
        *(ushort4*)(Tp + (size_t)bh * 65536 +
                    ((size_t)(pt * 2 + ks) * 64 + grpp * 16 + li) * 8 +
                    (grp & 1) * 4) = o;
      }
    }
  } else {
    // V: D rows = pos (4grp+r), cols = ch (li); sigma-permuted column store.
#pragma unroll
    for (int mt = 0; mt < 4; ++mt) {
      const int mbase = m0 + mt * 16;
      const int head = (mbase >> 6) & 3;
      const int bh = b * 4 + head;
      const int ct = (mbase & 63) >> 4;
      const float bvc = bias[mbase + li];
      const int kvt = n0 >> 5;
#pragma unroll
      for (int nt = 0; nt < 2; ++nt) {
        ushort4 o;
        o.x = f2bf(acc[mt][nt][0] + bvc);
        o.y = f2bf(acc[mt][nt][1] + bvc);
        o.z = f2bf(acc[mt][nt][2] + bvc);
        o.w = f2bf(acc[mt][nt][3] + bvc);
        *(ushort4*)(Vp + (size_t)bh * 65536 +
                    ((size_t)(ct * 32 + kvt) * 64 + grp * 16 + li) * 8 +
                    nt * 4) = o;
      }
    }
  }
}

// ---------------------------------------------------------------------------
// Flash attention, LDS-shared K/V via REG-STAGED double buffer:
//  top of iter t: issue global->reg loads of tile t+1 (wave w owns frag w);
//  compute tile t from LDS (ds_read_b128, conflict-free);
//  ds_write staged regs -> other buffer (vmcnt wait lands after compute);
//  one __syncthreads per iter (lgkm drain only — no vmcnt drain stall).
// Traffic: 4x less L2 than private streams. Block = (bh, 64 q), 4 waves.
// ---------------------------------------------------------------------------
__global__ __launch_bounds__(256) void attn_kernel(
    const unsigned short* __restrict__ Qp, const unsigned short* __restrict__ Kp,
    const unsigned short* __restrict__ Vp, unsigned short* __restrict__ aoTp) {
  __shared__ __align__(16) unsigned short Kl[2][2048];   // 4KB tile x2
  __shared__ __align__(16) unsigned short Vl[2][2048];
  const int bid = blockIdx.x;
  const int xcd = bid & 7, idx = bid >> 3;   // idx 0..63
  const int bh = xcd * 4 + (idx & 3);        // batch b = xcd
  const int qb = idx >> 2;                   // 0..15
  const int b = bh >> 2, head = bh & 3;
  const int t = threadIdx.x;
  const int wave = t >> 6, lane = t & 63;
  const int li = lane & 15, grp = lane >> 4;
  const int q0 = qb * 64 + wave * 16;
  const unsigned short* __restrict__ Qb = Qp + (size_t)bh * 65536;
  const unsigned short* __restrict__ Kb = Kp + (size_t)bh * 65536;
  const unsigned short* __restrict__ Vb = Vp + (size_t)bh * 65536;

  s16x8 qf[2];
#pragma unroll
  for (int ks = 0; ks < 2; ++ks)
    qf[ks] = *(const s16x8*)(Qb + (((q0 >> 4) * 2 + ks) * 64 + lane) * 8);

  f32x4 O[4];
#pragma unroll
  for (int ct = 0; ct < 4; ++ct) O[ct] = f32x4{0.f, 0.f, 0.f, 0.f};
  f32x4 lvec = f32x4{0.f, 0.f, 0.f, 0.f};
  float m_run = -1.0e30f;

  // wave w stages K frag w and V frag ct=w of tile `it` (16B/lane each).
  // it=32 overreads into the adjacent allocated ws region (never consumed).
  s16x8 kst, vst;
  auto stage_issue = [&](int it) {
    kst = *(const s16x8*)(Kb + ((size_t)(it * 4 + wave) * 512 + lane * 8));
    vst = *(const s16x8*)(Vb + ((size_t)(wave * 32 + it) * 512 + lane * 8));
  };
  auto stage_write = [&](int nb) {
    *(s16x8*)&Kl[nb][wave * 512 + lane * 8] = kst;
    *(s16x8*)&Vl[nb][wave * 512 + lane * 8] = vst;
  };

  stage_issue(0);
  stage_write(0);
  __syncthreads();

  int cb = 0;
#pragma unroll 1
  for (int it = 0; it < 32; ++it) {
    stage_issue(it + 1);   // global->reg, latency hidden under this iter
    // tile t frags from LDS (conflict-free b128 reads)
    s16x8 kk[2][2];
#pragma unroll
    for (int mt = 0; mt < 2; ++mt)
#pragma unroll
      for (int ks = 0; ks < 2; ++ks)
        kk[mt][ks] = *(const s16x8*)&Kl[cb][(mt * 2 + ks) * 512 + lane * 8];
    s16x8 vv[4];
#pragma unroll
    for (int ct = 0; ct < 4; ++ct)
      vv[ct] = *(const s16x8*)&Vl[cb][ct * 512 + lane * 8];
    // QK^T (rows j, col q), exp2 units
    f32x4 s[2];
    __builtin_amdgcn_s_setprio(1);
#pragma unroll
    for (int mt = 0; mt < 2; ++mt) {
      s[mt] = mfma16(kk[mt][0], qf[0], f32x4{0.f, 0.f, 0.f, 0.f});
      s[mt] = mfma16(kk[mt][1], qf[1], s[mt]);
    }
    __builtin_amdgcn_s_setprio(0);
    // online softmax (defer-max)
    const float A = fmaxf(fmaxf(s[0][0], s[0][1]), s[0][2]);
    const float B = fmaxf(fmaxf(s[0][3], s[1][0]), s[1][1]);
    const float C = fmaxf(fmaxf(s[1][2], s[1][3]), A);
    float pm = fmaxf(B, C);
    pm = fmaxf(pm, __shfl_xor(pm, 16));
    pm = fmaxf(pm, __shfl_xor(pm, 32));
    if (!__all(pm <= m_run + 8.0f)) {
      const float mnew = fmaxf(m_run, pm);
      const float f = exp2_fast(m_run - mnew);
      m_run = mnew;
      lvec *= f;
#pragma unroll
      for (int ct = 0; ct < 4; ++ct) O[ct] *= f;
    }
    f32x4 p[2];
#pragma unroll
    for (int mt = 0; mt < 2; ++mt) {
#pragma unroll
      for (int r = 0; r < 4; ++r) p[mt][r] = exp2_fast(s[mt][r] - m_run);
      lvec += p[mt];
    }
    u32x4 pk;
    pk[0] = cvt_pk_bf16(p[0][0], p[0][1]);
    pk[1] = cvt_pk_bf16(p[0][2], p[0][3]);
    pk[2] = cvt_pk_bf16(p[1][0], p[1][1]);
    pk[3] = cvt_pk_bf16(p[1][2], p[1][3]);
    const s16x8 pf = __builtin_bit_cast(s16x8, pk);
    __builtin_amdgcn_s_setprio(1);
#pragma unroll
    for (int ct = 0; ct < 4; ++ct) O[ct] = mfma16(vv[ct], pf, O[ct]);
    __builtin_amdgcn_s_setprio(0);
    // commit staged tile t+1 (vmcnt wait here, after ~300cy of compute)
    stage_write(cb ^ 1);
    __syncthreads();
    cb ^= 1;
  }

  float lt = lvec[0] + lvec[1] + lvec[2] + lvec[3];
  lt += __shfl_xor(lt, 16);
  lt += __shfl_xor(lt, 32);
  const float rinv = 1.f / lt;
  // write aoTp packed frags: q = q0+li, c = head*64 + ct*16 + 4*grp + r
#pragma unroll
  for (int ct = 0; ct < 4; ++ct) {
    const int ktp = head * 2 + (ct >> 1);
    const int grpp = ((ct & 1) * 2 + (grp >> 1)) & 3;
    ushort4 o;
    o.x = f2bf(O[ct][0] * rinv);
    o.y = f2bf(O[ct][1] * rinv);
    o.z = f2bf(O[ct][2] * rinv);
    o.w = f2bf(O[ct][3] * rinv);
    *(ushort4*)(aoTp +
                ((size_t)((b * 64 + (q0 >> 4)) * 8 + ktp) * 64 + grpp * 16 + li) * 8 +
                (grp & 1) * 4) = o;
  }
}

// ---------------------------------------------------------------------------
// Proj GEMM: 128m x 64n tiles, K=256, fp32 + bias + residual epilogue.
// ---------------------------------------------------------------------------
__global__ __launch_bounds__(256) void gemm_proj_kernel(
    const unsigned short* __restrict__ Wpp, const float* __restrict__ bias,
    const unsigned short* __restrict__ aoTp, const float* __restrict__ res,
    float* __restrict__ outp) {
  const int bid = blockIdx.x;
  const int swz = (bid & 7) * 32 + (bid >> 3);   // 256 blocks, batch = XCD
  const int b = swz >> 5, rr = swz & 31;
  const int mb = rr >> 4, nb = rr & 15;
  const int t = threadIdx.x;
  const int wave = t >> 6, lane = t & 63;
  const int li = lane & 15, grp = lane >> 4;
  const int m0 = mb * 128 + (wave >> 1) * 64;
  const int n0 = nb * 64 + (wave & 1) * 32;
  const int Mt0 = m0 >> 4;
  const int Nt0 = b * 64 + (n0 >> 4);
  const s16x8* __restrict__ Af = (const s16x8*)Wpp;
  const s16x8* __restrict__ Bf = (const s16x8*)aoTp;

  f32x4 acc[4][2];
#pragma unroll
  for (int mt = 0; mt < 4; ++mt)
#pragma unroll
    for (int nt = 0; nt < 2; ++nt) acc[mt][nt] = f32x4{0.f, 0.f, 0.f, 0.f};

  s16x8 sa[4][4], sb[4][2];
  gload(Af, Bf, Mt0, Nt0, 0, lane, sa[0], sb[0]);
  gload(Af, Bf, Mt0, Nt0, 1, lane, sa[1], sb[1]);
  gload(Af, Bf, Mt0, Nt0, 2, lane, sa[2], sb[2]);
#pragma unroll
  for (int kt = 0; kt < 8; ++kt) {
    if (kt + 3 < 8)
      gload(Af, Bf, Mt0, Nt0, kt + 3, lane, sa[(kt + 3) & 3], sb[(kt + 3) & 3]);
    gmfma(sa[kt & 3], sb[kt & 3], acc, false);
  }

#pragma unroll
  for (int mt = 0; mt < 4; ++mt) {
    const int mbase = m0 + mt * 16 + 4 * grp;
    const float4 bv = *(const float4*)(bias + mbase);
    const float bvr[4] = {bv.x, bv.y, bv.z, bv.w};
#pragma unroll
    for (int nt = 0; nt < 2; ++nt) {
      const int pos = n0 + nt * 16 + li;
#pragma unroll
      for (int r = 0; r < 4; ++r) {
        const size_t ob = ((size_t)(b * 256 + mbase + r)) * 1024 + pos;
        outp[ob] = acc[mt][nt][r] + bvr[r] + res[ob];
      }
    }
  }
}

// ---------------------------------------------------------------------------
extern "C" void kernel_launch(void* const* d_in, const int* in_sizes, int n_in,
                              void* d_out, int out_size, void* d_ws, size_t ws_size,
                              hipStream_t stream) {
  const float* x      = (const float*)d_in[0];
  const float* gamma  = (const float*)d_in[1];
  const float* beta   = (const float*)d_in[2];
  const float* w_qkv  = (const float*)d_in[3];
  const float* b_qkv  = (const float*)d_in[4];
  const float* w_proj = (const float*)d_in[5];
  const float* b_proj = (const float*)d_in[6];
  float* out = (float*)d_out;

  unsigned short* ws = (unsigned short*)d_ws;
  unsigned short* Wqp  = ws;                    // 196608
  unsigned short* Wpp  = Wqp + 196608;          // 65536
  unsigned short* hTp  = Wpp + 65536;           // 2097152
  unsigned short* Qp   = hTp + 2097152;         // 2097152
  unsigned short* Kp   = Qp + 2097152;          // 2097152
  unsigned short* Vp   = Kp + 2097152;          // 2097152
  unsigned short* aoTp = Vp + 2097152;          // 2097152

  hipLaunchKernelGGL(prep_kernel, dim3(384), dim3(256), 0, stream,
                     x, gamma, beta, hTp, w_qkv, w_proj, Wqp, Wpp);
  hipLaunchKernelGGL(gemm_qkv_kernel, dim3(768), dim3(256), 0, stream,
                     Wqp, b_qkv, hTp, Qp, Kp, Vp);
  hipLaunchKernelGGL(attn_kernel, dim3(512), dim3(256), 0, stream,
                     Qp, Kp, Vp, aoTp);
  hipLaunchKernelGGL(gemm_proj_kernel, dim3(256), dim3(256), 0, stream,
                     Wpp, b_proj, aoTp, x, out);
}

// Round 13
// 42.483 us; speedup vs baseline: 1.2019x; 1.0961x over previous
//
#include <hip/hip_runtime.h>
#include <hip/hip_bf16.h>

static constexpr int kC = 256;
static constexpr int kN = 1024;   // H*W

using s16x8 = __attribute__((ext_vector_type(8))) short;
using f32x4 = __attribute__((ext_vector_type(4))) float;
using u32x4 = __attribute__((ext_vector_type(4))) unsigned int;

__device__ inline f32x4 mfma16(s16x8 a, s16x8 b, f32x4 c) {
  return __builtin_amdgcn_mfma_f32_16x16x32_bf16(a, b, c, 0, 0, 0);
}

__device__ inline unsigned short f2bf(float f) {   // RNE
  unsigned u = __builtin_bit_cast(unsigned, f);
  u = (u + 0x7fffu + ((u >> 16) & 1u)) >> 16;
  return (unsigned short)u;
}

__device__ inline float exp2_fast(float x) {   // 2^x, single v_exp_f32
  float r;
  asm("v_exp_f32 %0, %1" : "=v"(r) : "v"(x));
  return r;
}

__device__ inline unsigned cvt_pk_bf16(float lo, float hi) {
  unsigned r;
  asm("v_cvt_pk_bf16_f32 %0, %1, %2" : "=v"(r) : "v"(lo), "v"(hi));
  return r;
}

// 1/sqrt(64) * log2(e): folded into Q so QK^T lands in exp2 units.
static constexpr float kQScale = 0.18033688011112042f;

// ---------------------------------------------------------------------------
// prep: blocks 0..127 pack weights into A-frag layout; blocks 128..383 GN.
// ---------------------------------------------------------------------------
__global__ __launch_bounds__(256) void prep_kernel(
    const float* __restrict__ x, const float* __restrict__ gamma,
    const float* __restrict__ beta, unsigned short* __restrict__ hTp,
    const float* __restrict__ wq, const float* __restrict__ wp,
    unsigned short* __restrict__ Wqp, unsigned short* __restrict__ Wpp) {
  if (blockIdx.x < 128) {
    const int tid = blockIdx.x * 256 + threadIdx.x;   // 0..32767
    const float* src;
    unsigned short* dst;
    if (tid < 24576) {
      const int fragid = tid >> 6, lane = tid & 63;
      const int Mt = fragid >> 3, kt = fragid & 7;
      src = wq + (size_t)(Mt * 16 + (lane & 15)) * 256 + kt * 32 + (lane >> 4) * 8;
      dst = Wqp + (size_t)tid * 8;
    } else {
      const int id = tid - 24576;
      const int fragid = id >> 6, lane = id & 63;
      const int Mt = fragid >> 3, kt = fragid & 7;
      src = wp + (size_t)(Mt * 16 + (lane & 15)) * 256 + kt * 32 + (lane >> 4) * 8;
      dst = Wpp + (size_t)id * 8;
    }
    const float4 f0 = *(const float4*)src;
    const float4 f1 = *(const float4*)(src + 4);
    ushort4 o0, o1;
    o0.x = f2bf(f0.x); o0.y = f2bf(f0.y); o0.z = f2bf(f0.z); o0.w = f2bf(f0.w);
    o1.x = f2bf(f1.x); o1.y = f2bf(f1.y); o1.z = f2bf(f1.z); o1.w = f2bf(f1.w);
    *(ushort4*)dst = o0;
    *(ushort4*)(dst + 4) = o1;
    return;
  }

  const int bg = blockIdx.x - 128;
  const int b = bg & 7, g = bg >> 3;   // batch = XCD
  const size_t base = ((size_t)b * kC + (size_t)g * 8) * kN;
  const float4* __restrict__ x4 = (const float4*)(x + base);
  const int t = threadIdx.x;

  float vv[8][4];
  float s = 0.f, ss = 0.f;
#pragma unroll
  for (int i = 0; i < 8; ++i) {
    const float4 v = x4[t + 256 * i];
    vv[i][0] = v.x; vv[i][1] = v.y; vv[i][2] = v.z; vv[i][3] = v.w;
    s += v.x + v.y + v.z + v.w;
    ss += v.x * v.x + v.y * v.y + v.z * v.z + v.w * v.w;
  }
#pragma unroll
  for (int off = 32; off > 0; off >>= 1) {
    s += __shfl_xor(s, off);
    ss += __shfl_xor(ss, off);
  }
  __shared__ float rs[4], rss[4];
  const int wave = t >> 6, lane = t & 63;
  if (lane == 0) { rs[wave] = s; rss[wave] = ss; }
  __syncthreads();
  s = rs[0] + rs[1] + rs[2] + rs[3];
  ss = rss[0] + rss[1] + rss[2] + rss[3];
  const float mean = s * (1.f / 8192.f);
  const float var = ss * (1.f / 8192.f) - mean * mean;
  const float rinv = rsqrtf(var + 1e-5f);
  float ga[8], be[8];
#pragma unroll
  for (int i = 0; i < 8; ++i) {
    ga[i] = gamma[g * 8 + i] * rinv;
    be[i] = beta[g * 8 + i] - mean * ga[i];
  }
  const int kt = g >> 2, gq = g & 3;
#pragma unroll
  for (int r = 0; r < 4; ++r) {
    const int pos = 4 * t + r;
    const int nt = pos >> 4, lp = pos & 15;
    unsigned short* dst =
        hTp + ((size_t)((b * 64 + nt) * 8 + kt) * 64 + (gq * 16 + lp)) * 8;
    ushort4 o0, o1;
    o0.x = f2bf(vv[0][r] * ga[0] + be[0]);
    o0.y = f2bf(vv[1][r] * ga[1] + be[1]);
    o0.z = f2bf(vv[2][r] * ga[2] + be[2]);
    o0.w = f2bf(vv[3][r] * ga[3] + be[3]);
    o1.x = f2bf(vv[4][r] * ga[4] + be[4]);
    o1.y = f2bf(vv[5][r] * ga[5] + be[5]);
    o1.z = f2bf(vv[6][r] * ga[6] + be[6]);
    o1.w = f2bf(vv[7][r] * ga[7] + be[7]);
    *(ushort4*)dst = o0;
    *(ushort4*)(dst + 4) = o1;
  }
}

// ---------------------------------------------------------------------------
// LDS-free bf16 MFMA QKV GEMM, depth-3 register prefetch (4 rotating slots).
// V stored sigma-permuted so attention's P registers are directly the PV
// B-frag (no LDS round trip).
// ---------------------------------------------------------------------------
__device__ inline void gload(const s16x8* __restrict__ Af,
                             const s16x8* __restrict__ Bf,
                             int Mt0, int Nt0, int kt, int lane,
                             s16x8 (&a)[4], s16x8 (&bb)[2]) {
#pragma unroll
  for (int mt = 0; mt < 4; ++mt)
    a[mt] = Af[((size_t)(Mt0 + mt) * 8 + kt) * 64 + lane];
#pragma unroll
  for (int nt = 0; nt < 2; ++nt)
    bb[nt] = Bf[((size_t)(Nt0 + nt) * 8 + kt) * 64 + lane];
}

__device__ inline void gmfma(const s16x8 (&a)[4], const s16x8 (&bb)[2],
                             f32x4 (&acc)[4][2], bool swap) {
  if (swap) {
#pragma unroll
    for (int mt = 0; mt < 4; ++mt)
#pragma unroll
      for (int nt = 0; nt < 2; ++nt)
        acc[mt][nt] = mfma16(bb[nt], a[mt], acc[mt][nt]);
  } else {
#pragma unroll
    for (int mt = 0; mt < 4; ++mt)
#pragma unroll
      for (int nt = 0; nt < 2; ++nt)
        acc[mt][nt] = mfma16(a[mt], bb[nt], acc[mt][nt]);
  }
}

__global__ __launch_bounds__(256) void gemm_qkv_kernel(
    const unsigned short* __restrict__ Wp, const float* __restrict__ bias,
    const unsigned short* __restrict__ Bp,
    unsigned short* __restrict__ Qp, unsigned short* __restrict__ Kp,
    unsigned short* __restrict__ Vp) {
  const int bid = blockIdx.x;
  const int swz = (bid & 7) * 96 + (bid >> 3);
  const int b = swz / 96, rr = swz % 96;
  const int mb = rr >> 4, nb = rr & 15;
  const int t = threadIdx.x;
  const int wave = t >> 6, lane = t & 63;
  const int li = lane & 15, grp = lane >> 4;
  const int m0 = mb * 128 + (wave >> 1) * 64;
  const int n0 = nb * 64 + (wave & 1) * 32;
  const bool swap = mb >= 4;   // V tiles
  const int Mt0 = m0 >> 4;
  const int Nt0 = b * 64 + (n0 >> 4);
  const s16x8* __restrict__ Af = (const s16x8*)Wp;
  const s16x8* __restrict__ Bf = (const s16x8*)Bp;

  f32x4 acc[4][2];
#pragma unroll
  for (int mt = 0; mt < 4; ++mt)
#pragma unroll
    for (int nt = 0; nt < 2; ++nt) acc[mt][nt] = f32x4{0.f, 0.f, 0.f, 0.f};

  s16x8 sa[4][4], sb[4][2];   // 4 rotating slots, depth-3 prefetch
  gload(Af, Bf, Mt0, Nt0, 0, lane, sa[0], sb[0]);
  gload(Af, Bf, Mt0, Nt0, 1, lane, sa[1], sb[1]);
  gload(Af, Bf, Mt0, Nt0, 2, lane, sa[2], sb[2]);
#pragma unroll
  for (int kt = 0; kt < 8; ++kt) {
    if (kt + 3 < 8)
      gload(Af, Bf, Mt0, Nt0, kt + 3, lane, sa[(kt + 3) & 3], sb[(kt + 3) & 3]);
    gmfma(sa[kt & 3], sb[kt & 3], acc, swap);
  }

  if (!swap) {
    // Q/K: D rows = ch (4grp+r), cols = pos (li). Q gets kQScale folded in.
    unsigned short* __restrict__ Tp = (mb < 2) ? Qp : Kp;
    const float qs = (mb < 2) ? kQScale : 1.0f;
#pragma unroll
    for (int mt = 0; mt < 4; ++mt) {
      const int mbase = m0 + mt * 16;
      const int head = (mbase >> 6) & 3;
      const int bh = b * 4 + head;
      const int c16 = mbase & 63;
      const int ks = c16 >> 5;
      const int grpp = ((c16 >> 3) + (grp >> 1)) & 3;
      const float4 bv = *(const float4*)(bias + mbase + 4 * grp);
#pragma unroll
      for (int nt = 0; nt < 2; ++nt) {
        const int pt = (n0 >> 4) + nt;
        ushort4 o;
        o.x = f2bf((acc[mt][nt][0] + bv.x) * qs);
        o.y = f2bf((acc[mt][nt][1] + bv.y) * qs);
        o.z = f2bf((acc[mt][nt][2] + bv.z) * qs);
        o.w = f2bf((acc[mt][nt][3] + bv.w) * qs);
        *(ushort4*)(Tp + (size_t)bh * 65536 +
                    ((size_t)(pt * 2 + ks) * 64 + grpp * 16 + li) * 8 +
                    (grp & 1) * 4) = o;
      }
    }
  } else {
    // V: D rows = pos (4grp+r), cols = ch (li); sigma-permuted column store.
#pragma unroll
    for (int mt = 0; mt < 4; ++mt) {
      const int mbase = m0 + mt * 16;
      const int head = (mbase >> 6) & 3;
      const int bh = b * 4 + head;
      const int ct = (mbase & 63) >> 4;
      const float bvc = bias[mbase + li];
      const int kvt = n0 >> 5;
#pragma unroll
      for (int nt = 0; nt < 2; ++nt) {
        ushort4 o;
        o.x = f2bf(acc[mt][nt][0] + bvc);
        o.y = f2bf(acc[mt][nt][1] + bvc);
        o.z = f2bf(acc[mt][nt][2] + bvc);
        o.w = f2bf(acc[mt][nt][3] + bvc);
        *(ushort4*)(Vp + (size_t)bh * 65536 +
                    ((size_t)(ct * 32 + kvt) * 64 + grp * 16 + li) * 8 +
                    nt * 4) = o;
      }
    }
  }
}

// ---------------------------------------------------------------------------
// K-split fused flash-attention + proj. 512 blocks x 512 threads, 2 blk/CU
// (=16 waves/CU, double R9's TLP). Block = (b, 16 positions); 8 waves =
// 4 heads x 2 K-halves; each wave runs 16 KV tiles (no prefetch regs — TLP
// hides latency). Partials merged per head via LDS + exact exp2 rescale,
// then all 8 waves compute the proj on the 16-position tile.
// ---------------------------------------------------------------------------
__global__ __launch_bounds__(512, 4) void attn_proj_kernel(
    const unsigned short* __restrict__ Qp, const unsigned short* __restrict__ Kp,
    const unsigned short* __restrict__ Vp, const unsigned short* __restrict__ Wpp,
    const float* __restrict__ bpj, const float* __restrict__ x,
    float* __restrict__ out) {
  __shared__ __align__(16) float Ml[4][64][18];              // 18 KB partials
  __shared__ __align__(16) unsigned short Ex[8][64][8];      // 8 KB proj B-frags
  const int bid = blockIdx.x;
  const int b = bid & 7;                    // batch = XCD
  const int pb = bid >> 3;                  // 16-position block, 0..63
  const int q0 = pb * 16;
  const int t = threadIdx.x;
  const int w8 = t >> 6, lane = t & 63;
  const int head = w8 & 3, khalf = w8 >> 2;
  const int li = lane & 15, grp = lane >> 4;
  const int bh = b * 4 + head;
  const unsigned short* __restrict__ Qb = Qp + (size_t)bh * 65536;
  const unsigned short* __restrict__ Kb = Kp + (size_t)bh * 65536;
  const unsigned short* __restrict__ Vb = Vp + (size_t)bh * 65536;

  s16x8 qf[2];
#pragma unroll
  for (int ks = 0; ks < 2; ++ks)
    qf[ks] = *(const s16x8*)(Qb + ((pb * 2 + ks) * 64 + lane) * 8);

  f32x4 O[4];
#pragma unroll
  for (int ct = 0; ct < 4; ++ct) O[ct] = f32x4{0.f, 0.f, 0.f, 0.f};
  f32x4 lvec = f32x4{0.f, 0.f, 0.f, 0.f};
  float m_run = -1.0e30f;
  const int kbase = khalf * 16;

#pragma unroll 1
  for (int i2 = 0; i2 < 16; ++i2) {
    const int it = kbase + i2;
    // K and V frags for this tile (issued together; V waited late at PV)
    s16x8 kk[2][2];
#pragma unroll
    for (int mt = 0; mt < 2; ++mt)
#pragma unroll
      for (int ks = 0; ks < 2; ++ks)
        kk[mt][ks] = *(const s16x8*)(
            Kb + ((size_t)((it * 2 + mt) * 2 + ks) * 64 + lane) * 8);
    s16x8 vv[4];
#pragma unroll
    for (int ct = 0; ct < 4; ++ct)
      vv[ct] = *(const s16x8*)(Vb + ((size_t)(ct * 32 + it) * 64 + lane) * 8);
    // QK^T (rows j, col q), exp2 units
    f32x4 s[2];
    __builtin_amdgcn_s_setprio(1);
#pragma unroll
    for (int mt = 0; mt < 2; ++mt) {
      s[mt] = mfma16(kk[mt][0], qf[0], f32x4{0.f, 0.f, 0.f, 0.f});
      s[mt] = mfma16(kk[mt][1], qf[1], s[mt]);
    }
    __builtin_amdgcn_s_setprio(0);
    // online softmax (defer-max)
    const float A = fmaxf(fmaxf(s[0][0], s[0][1]), s[0][2]);
    const float B = fmaxf(fmaxf(s[0][3], s[1][0]), s[1][1]);
    const float C = fmaxf(fmaxf(s[1][2], s[1][3]), A);
    float pm = fmaxf(B, C);
    pm = fmaxf(pm, __shfl_xor(pm, 16));
    pm = fmaxf(pm, __shfl_xor(pm, 32));
    if (!__all(pm <= m_run + 8.0f)) {
      const float mnew = fmaxf(m_run, pm);
      const float f = exp2_fast(m_run - mnew);
      m_run = mnew;
      lvec *= f;
#pragma unroll
      for (int ct = 0; ct < 4; ++ct) O[ct] *= f;
    }
    f32x4 p[2];
#pragma unroll
    for (int mt = 0; mt < 2; ++mt) {
#pragma unroll
      for (int r = 0; r < 4; ++r) p[mt][r] = exp2_fast(s[mt][r] - m_run);
      lvec += p[mt];
    }
    // P -> bf16 PV B-frag entirely in registers (sigma-permuted V)
    u32x4 pk;
    pk[0] = cvt_pk_bf16(p[0][0], p[0][1]);
    pk[1] = cvt_pk_bf16(p[0][2], p[0][3]);
    pk[2] = cvt_pk_bf16(p[1][0], p[1][1]);
    pk[3] = cvt_pk_bf16(p[1][2], p[1][3]);
    const s16x8 pf = __builtin_bit_cast(s16x8, pk);
    __builtin_amdgcn_s_setprio(1);
#pragma unroll
    for (int ct = 0; ct < 4; ++ct) O[ct] = mfma16(vv[ct], pf, O[ct]);
    __builtin_amdgcn_s_setprio(0);
  }

  // per-wave l over its K-half (per q = li, replicated across grp)
  float lt = lvec[0] + lvec[1] + lvec[2] + lvec[3];
  lt += __shfl_xor(lt, 16);
  lt += __shfl_xor(lt, 32);

  // ---- merge K-halves per head ----
  if (khalf == 1) {
    float* dst = &Ml[head][lane][0];
#pragma unroll
    for (int ct = 0; ct < 4; ++ct) *(f32x4*)(dst + ct * 4) = O[ct];
    dst[16] = m_run;
    dst[17] = lt;
  }
  __syncthreads();
  if (khalf == 0) {
    const float* src = &Ml[head][lane][0];
    const float mB = src[16], lB = src[17];
    const float mS = fmaxf(m_run, mB);
    const float fA = exp2_fast(m_run - mS);
    const float fB = exp2_fast(mB - mS);
    const float rinv = 1.f / (lt * fA + lB * fB);
    const float a = fA * rinv, bs = fB * rinv;
#pragma unroll
    for (int ct = 0; ct < 4; ++ct) {
      const f32x4 ob = *(const f32x4*)(src + ct * 4);
      ushort4 o;
      o.x = f2bf(O[ct][0] * a + ob[0] * bs);
      o.y = f2bf(O[ct][1] * a + ob[1] * bs);
      o.z = f2bf(O[ct][2] * a + ob[2] * bs);
      o.w = f2bf(O[ct][3] * a + ob[3] * bs);
      const int ktp = head * 2 + (ct >> 1);
      const int grpp = ((ct & 1) * 2 + (grp >> 1)) & 3;
      *(ushort4*)&Ex[ktp][grpp * 16 + li][(grp & 1) * 4] = o;
    }
  }
  __syncthreads();

  // ---- proj: wave w8 computes out rows w8*32 .. +31, 16 positions ----
  {
    const int Mt0 = w8 * 2;
    const s16x8* __restrict__ Af = (const s16x8*)Wpp;
    f32x4 acc[2];
    acc[0] = f32x4{0.f, 0.f, 0.f, 0.f};
    acc[1] = f32x4{0.f, 0.f, 0.f, 0.f};

    s16x8 pa[3][2];
    auto loadA = [&](int kt, s16x8 (&a)[2]) {
#pragma unroll
      for (int mt = 0; mt < 2; ++mt)
        a[mt] = Af[((size_t)(Mt0 + mt) * 8 + kt) * 64 + lane];
    };
    loadA(0, pa[0]);
    loadA(1, pa[1]);
#pragma unroll
    for (int kt = 0; kt < 8; ++kt) {
      if (kt + 2 < 8) loadA(kt + 2, pa[(kt + 2) % 3]);
      const s16x8 bb = *(const s16x8*)&Ex[kt][lane][0];
#pragma unroll
      for (int mt = 0; mt < 2; ++mt)
        acc[mt] = mfma16(pa[kt % 3][mt], bb, acc[mt]);
    }

#pragma unroll
    for (int mt = 0; mt < 2; ++mt) {
      const int mbase = w8 * 32 + mt * 16 + 4 * grp;
      const float4 bv = *(const float4*)(bpj + mbase);
      const float bvr[4] = {bv.x, bv.y, bv.z, bv.w};
      const int pos = q0 + li;
#pragma unroll
      for (int r2 = 0; r2 < 4; ++r2) {
        const size_t ob = ((size_t)(b * 256 + mbase + r2)) * 1024 + pos;
        out[ob] = acc[mt][r2] + bvr[r2] + x[ob];
      }
    }
  }
}

// ---------------------------------------------------------------------------
extern "C" void kernel_launch(void* const* d_in, const int* in_sizes, int n_in,
                              void* d_out, int out_size, void* d_ws, size_t ws_size,
                              hipStream_t stream) {
  const float* x      = (const float*)d_in[0];
  const float* gamma  = (const float*)d_in[1];
  const float* beta   = (const float*)d_in[2];
  const float* w_qkv  = (const float*)d_in[3];
  const float* b_qkv  = (const float*)d_in[4];
  const float* w_proj = (const float*)d_in[5];
  const float* b_proj = (const float*)d_in[6];
  float* out = (float*)d_out;

  unsigned short* ws = (unsigned short*)d_ws;
  unsigned short* Wqp  = ws;                    // 196608
  unsigned short* Wpp  = Wqp + 196608;          // 65536
  unsigned short* hTp  = Wpp + 65536;           // 2097152
  unsigned short* Qp   = hTp + 2097152;         // 2097152
  unsigned short* Kp   = Qp + 2097152;          // 2097152
  unsigned short* Vp   = Kp + 2097152;          // 2097152

  hipLaunchKernelGGL(prep_kernel, dim3(384), dim3(256), 0, stream,
                     x, gamma, beta, hTp, w_qkv, w_proj, Wqp, Wpp);
  hipLaunchKernelGGL(gemm_qkv_kernel, dim3(768), dim3(256), 0, stream,
                     Wqp, b_qkv, hTp, Qp, Kp, Vp);
  hipLaunchKernelGGL(attn_proj_kernel, dim3(512), dim3(512), 0, stream,
                     Qp, Kp, Vp, Wpp, b_proj, x, out);
}